// Round 1
// baseline (136.542 us; speedup 1.0000x reference)
//
#include <hip/hip_runtime.h>
#include <math.h>

#define IMG 256
#define NB  64
#define NGF 64

// ---------------- Kernel 1: gating conv 7x7 stride 4 + relu + partial sums -----
// grid (8 row-tiles, 64 batch), 256 threads
__global__ __launch_bounds__(256) void gate_conv_kernel(
    const float* __restrict__ x, const float* __restrict__ Wg,
    float* __restrict__ partials)
{
    __shared__ float xs[35 * 260];      // x[tile*32-1 + r][c-1], zero-padded
    __shared__ float wshT[49 * 64];     // wshT[k][gf]

    const int tile = blockIdx.x;
    const int b    = blockIdx.y;
    const int tid  = threadIdx.x;

    for (int i = tid; i < 49 * 64; i += 256) {
        int k = i >> 6, gf = i & 63;
        wshT[i] = Wg[gf * 49 + k];
    }
    const float* xb = x + (size_t)b * (IMG * IMG);
    const int iy0 = tile * 32 - 1;
    for (int i = tid; i < 35 * 260; i += 256) {
        int r = i / 260, c = i - r * 260;
        int iy = iy0 + r, ix = c - 1;
        float v = 0.f;
        if (iy >= 0 && iy < IMG && ix >= 0 && ix < IMG) v = xb[iy * IMG + ix];
        xs[i] = v;
    }
    __syncthreads();

    const int gf4   = tid >> 4;   // 0..15 -> gf = gf4*4+g
    const int pslot = tid & 15;   // 0..15 -> ox = pslot + 16*p

    float rsum[4] = {0.f, 0.f, 0.f, 0.f};

    for (int pgb = 0; pgb < 2; ++pgb) {      // output rows pg = pgb*4 + q
        float acc[4][4][4];                  // [g][q][p]
        #pragma unroll
        for (int g = 0; g < 4; ++g)
            #pragma unroll
            for (int q = 0; q < 4; ++q)
                #pragma unroll
                for (int p = 0; p < 4; ++p) acc[g][q][p] = 0.f;

        for (int ky = 0; ky < 7; ++ky) {
            for (int kx = 0; kx < 7; ++kx) {
                const float4 w4 = *(const float4*)&wshT[(ky * 7 + kx) * 64 + (gf4 << 2)];
                #pragma unroll
                for (int q = 0; q < 4; ++q) {
                    const float* xr = &xs[((pgb * 4 + q) * 4 + ky) * 260 + (pslot << 2) + kx];
                    float xv[4] = {xr[0], xr[64], xr[128], xr[192]};
                    #pragma unroll
                    for (int p = 0; p < 4; ++p) {
                        const float xv_ = xv[p];
                        acc[0][q][p] += w4.x * xv_;
                        acc[1][q][p] += w4.y * xv_;
                        acc[2][q][p] += w4.z * xv_;
                        acc[3][q][p] += w4.w * xv_;
                    }
                }
            }
        }
        #pragma unroll
        for (int g = 0; g < 4; ++g)
            #pragma unroll
            for (int q = 0; q < 4; ++q)
                #pragma unroll
                for (int p = 0; p < 4; ++p)
                    rsum[g] += fmaxf(acc[g][q][p], 0.f);
    }

    // reduce over the 16 pslot lanes (contiguous within a wave)
    #pragma unroll
    for (int g = 0; g < 4; ++g) {
        float v = rsum[g];
        v += __shfl_xor(v, 8);
        v += __shfl_xor(v, 4);
        v += __shfl_xor(v, 2);
        v += __shfl_xor(v, 1);
        if (pslot == 0)
            partials[((b * 8 + tile) * 64) + (gf4 << 2) + g] = v;
    }
}

// ---------------- Kernel 2: gating finalize (feats -> heads -> weights) --------
__global__ void gate_finalize_kernel(
    const float* __restrict__ partials,
    const float* __restrict__ Wc, const float* __restrict__ bc,
    const float* __restrict__ Wp, const float* __restrict__ bp,
    int* __restrict__ gidx, float* __restrict__ gw)
{
    const int b = threadIdx.x;   // 64 threads
    float f[64];
    #pragma unroll
    for (int g = 0; g < 64; ++g) {
        float s = 0.f;
        #pragma unroll
        for (int t = 0; t < 8; ++t) s += partials[(b * 8 + t) * 64 + g];
        f[g] = s * (1.0f / 4096.0f);
    }
    float cl[6], pl[2];
    #pragma unroll
    for (int j = 0; j < 6; ++j) {
        float s = bc[j];
        #pragma unroll
        for (int g = 0; g < 64; ++g) s += f[g] * Wc[j * 64 + g];
        cl[j] = s;   // T = 1.0
    }
    #pragma unroll
    for (int j = 0; j < 2; ++j) {
        float s = bp[j];
        #pragma unroll
        for (int g = 0; g < 64; ++g) s += f[g] * Wp[j * 64 + g];
        pl[j] = s;
    }
    // parent softmax (2-way)
    const float pm = fmaxf(pl[0], pl[1]);
    const float e0 = expf(pl[0] - pm), e1 = expf(pl[1] - pm);
    const int   pi = (pl[1] > pl[0]) ? 1 : 0;          // first argmax on ties
    const float pv = fmaxf(e0, e1) / (e0 + e1);
    // child softmax (6-way)
    float cm = cl[0];
    #pragma unroll
    for (int j = 1; j < 6; ++j) cm = fmaxf(cm, cl[j]);
    float es = 0.f, ce[6];
    #pragma unroll
    for (int j = 0; j < 6; ++j) { ce[j] = expf(cl[j] - cm); es += ce[j]; }
    int ci = 0; float cbest = cl[0];
    #pragma unroll
    for (int j = 1; j < 6; ++j) if (cl[j] > cbest) { cbest = cl[j]; ci = j; }
    const float cv = ce[ci] / es;

    const float wp = 0.3f * pv;
    const float wc = 0.7f * cv;
    const float tot = wp + wc + 1e-8f;
    gidx[b]      = pi;
    gidx[64 + b] = ci + 2;
    gw[b]        = wp / tot;
    gw[64 + b]   = wc / tot;
}

// ---------------- Kernel 3: fused two-expert conv3x3 -> relu -> conv3x3 -------
// grid (64 tiles of 32x32, 64 batch), 256 threads
__global__ __launch_bounds__(256) void expert_kernel(
    const float* __restrict__ x,
    const float* __restrict__ We1, const float* __restrict__ be1,
    const float* __restrict__ We2, const float* __restrict__ be2,
    const int* __restrict__ gidx, const float* __restrict__ gw,
    float* __restrict__ out)
{
    __shared__ float xs[36 * 40];        // x tile + halo2, row stride 40
    __shared__ float hs[8 * 34 * 34];    // h tile + halo1, [ch][hy][hx]

    const int tile = blockIdx.x;
    const int b    = blockIdx.y;
    const int ty = tile >> 3, tx = tile & 7;
    const int y0 = ty * 32, x0 = tx * 32;
    const int tid = threadIdx.x;

    const float* xb = x + (size_t)b * (IMG * IMG);
    for (int i = tid; i < 36 * 40; i += 256) {
        int r = i / 40, c = i - r * 40;
        float v = 0.f;
        if (c < 36) {
            int gy = y0 - 2 + r, gx = x0 - 2 + c;
            if (gy >= 0 && gy < IMG && gx >= 0 && gx < IMG) v = xb[gy * IMG + gx];
        }
        xs[i] = v;
    }

    const int ep = gidx[b];
    const int ec = gidx[64 + b];
    const float wA = gw[b];
    const float wB = gw[64 + b];

    const int r_ = tid >> 3;          // 0..31 output row
    const int c0 = (tid & 7) << 2;    // output col group (4 cols)
    const int c1ch   = tid >> 5;      // conv1: channel 0..7
    const int lane32 = tid & 31;

    float oacc0 = 0.f, oacc1 = 0.f, oacc2 = 0.f, oacc3 = 0.f;

    __syncthreads();

    for (int ei = 0; ei < 2; ++ei) {
        const int   e   = ei ? ec : ep;
        const float wgt = ei ? wB : wA;

        // conv1 weights for my channel
        float w1r[9];
        const float* w1p = We1 + e * 72 + c1ch * 9;
        #pragma unroll
        for (int k = 0; k < 9; ++k) w1r[k] = w1p[k];
        const float b1r = be1[e * 8 + c1ch];

        if (ei) __syncthreads();   // prev conv2 reads done before hs overwrite

        // ---- conv1: h = relu(conv(x) + b1), zero outside image ----
        for (int j = lane32; j < 306; j += 32) {
            const int hy = j / 9;
            const int cb = (j - hy * 9) << 2;     // 0,4,...,32
            float a0 = b1r, a1 = b1r, a2 = b1r, a3 = b1r;
            #pragma unroll
            for (int ky = 0; ky < 3; ++ky) {
                const float* xr = &xs[(hy + ky) * 40 + cb];
                const float2 xa = *(const float2*)(xr);
                const float2 xb2 = *(const float2*)(xr + 2);
                const float2 xc2 = *(const float2*)(xr + 4);
                const float wa = w1r[ky * 3 + 0], wb = w1r[ky * 3 + 1], wcc = w1r[ky * 3 + 2];
                a0 += wa * xa.x  + wb * xa.y  + wcc * xb2.x;
                a1 += wa * xa.y  + wb * xb2.x + wcc * xb2.y;
                a2 += wa * xb2.x + wb * xb2.y + wcc * xc2.x;
                a3 += wa * xb2.y + wb * xc2.x + wcc * xc2.y;
            }
            const int gy = y0 - 1 + hy;
            const int gx = x0 - 1 + cb;
            const bool rowok = (gy >= 0) && (gy < IMG);
            const float h0 = (rowok && gx >= 0 && gx < IMG)     ? fmaxf(a0, 0.f) : 0.f;
            const float h1 = (rowok && (gx + 1) < IMG)          ? fmaxf(a1, 0.f) : 0.f;
            const float h2 = (rowok && (gx + 2) < IMG)          ? fmaxf(a2, 0.f) : 0.f;
            const float h3 = (rowok && (gx + 3) < IMG)          ? fmaxf(a3, 0.f) : 0.f;
            float* hp = &hs[c1ch * 1156 + hy * 34 + cb];
            *(float2*)hp = make_float2(h0, h1);
            if (cb < 32) *(float2*)(hp + 2) = make_float2(h2, h3);
        }
        __syncthreads();

        // ---- conv2: y = conv(h) + b2, accumulate with gate weight ----
        float a0 = 0.f, a1 = 0.f, a2 = 0.f, a3 = 0.f;
        #pragma unroll
        for (int ch = 0; ch < 8; ++ch) {
            const float* w2p = We2 + e * 72 + ch * 9;
            float w2r[9];
            #pragma unroll
            for (int k = 0; k < 9; ++k) w2r[k] = w2p[k];
            #pragma unroll
            for (int ky = 0; ky < 3; ++ky) {
                const float* hp = &hs[ch * 1156 + (r_ + ky) * 34 + c0];
                const float2 ha = *(const float2*)(hp);
                const float2 hb = *(const float2*)(hp + 2);
                const float2 hc = *(const float2*)(hp + 4);
                const float wa = w2r[ky * 3], wb = w2r[ky * 3 + 1], wcx = w2r[ky * 3 + 2];
                a0 += wa * ha.x + wb * ha.y + wcx * hb.x;
                a1 += wa * ha.y + wb * hb.x + wcx * hb.y;
                a2 += wa * hb.x + wb * hb.y + wcx * hc.x;
                a3 += wa * hb.y + wb * hc.x + wcx * hc.y;
            }
        }
        const float b2v = be2[e];
        oacc0 += wgt * (a0 + b2v);
        oacc1 += wgt * (a1 + b2v);
        oacc2 += wgt * (a2 + b2v);
        oacc3 += wgt * (a3 + b2v);
    }

    float4 o4 = make_float4(oacc0, oacc1, oacc2, oacc3);
    *(float4*)&out[(size_t)b * (IMG * IMG) + (y0 + r_) * IMG + (x0 + c0)] = o4;
}

extern "C" void kernel_launch(void* const* d_in, const int* in_sizes, int n_in,
                              void* d_out, int out_size, void* d_ws, size_t ws_size,
                              hipStream_t stream) {
    const float* x   = (const float*)d_in[0];
    const float* Wg  = (const float*)d_in[1];
    const float* Wc  = (const float*)d_in[2];
    const float* bc  = (const float*)d_in[3];
    const float* Wp  = (const float*)d_in[4];
    const float* bp  = (const float*)d_in[5];
    const float* We1 = (const float*)d_in[6];
    const float* be1 = (const float*)d_in[7];
    const float* We2 = (const float*)d_in[8];
    const float* be2 = (const float*)d_in[9];
    float* out = (float*)d_out;

    float* partials = (float*)d_ws;                              // 32768 floats
    int*   gidx     = (int*)((char*)d_ws + 131072);              // 128 ints
    float* gw       = (float*)((char*)d_ws + 131072 + 512);      // 128 floats

    gate_conv_kernel<<<dim3(8, 64), dim3(256), 0, stream>>>(x, Wg, partials);
    gate_finalize_kernel<<<dim3(1), dim3(64), 0, stream>>>(partials, Wc, bc, Wp, bp, gidx, gw);
    expert_kernel<<<dim3(64, 64), dim3(256), 0, stream>>>(x, We1, be1, We2, be2, gidx, gw, out);
}